// Round 9
// baseline (1005.739 us; speedup 1.0000x reference)
//
#include <hip/hip_runtime.h>

#define N_NODES 50000
#define N_EDGES 500000
#define EMB 50
#define HID 64
#define OUTD 50
#define EDIM 28
#define HEADS 4
#define F1 256              // HEADS*HID
#define NEG 0.2f
#define EPS_SM 1e-16f
#define EPS_LN 1e-5f

typedef unsigned short u16;
typedef unsigned int u32;

__device__ __forceinline__ float b2f(u16 u) { return __uint_as_float(((u32)u) << 16); }
__device__ __forceinline__ u16 f2b(float f) {
    u32 u = __float_as_uint(f);
    u32 r = (u + 0x7FFFu + ((u >> 16) & 1u)) >> 16;
    return (u16)r;
}
__device__ __forceinline__ float lrelu(float x) { return x > 0.f ? x : NEG * x; }

// ======================= CSR build =======================
__global__ void k_hist(const int* __restrict__ dst, int* __restrict__ cnt) {
    int e = blockIdx.x * blockDim.x + threadIdx.x;
    if (e < N_EDGES) atomicAdd(&cnt[dst[e]], 1);
}

__global__ __launch_bounds__(1024) void k_scan(const int* __restrict__ cnt, int* __restrict__ rowptr) {
    __shared__ int part[1024];
    int tid = threadIdx.x;
    const int CH = (N_NODES + 1023) / 1024;   // 49
    int beg = tid * CH;
    int end = beg + CH; if (end > N_NODES) end = N_NODES;
    int s = 0;
    for (int i = beg; i < end && i >= beg; i++) s += cnt[i];
    part[tid] = s;
    __syncthreads();
    for (int off = 1; off < 1024; off <<= 1) {
        int v = (tid >= off) ? part[tid - off] : 0;
        __syncthreads();
        part[tid] += v;
        __syncthreads();
    }
    int run = (tid == 0) ? 0 : part[tid - 1];
    for (int i = beg; i < end && i >= beg; i++) { rowptr[i] = run; run += cnt[i]; }
    if (tid == 1023) rowptr[N_NODES] = run;
}

__global__ void k_scatter(const int* __restrict__ src, const int* __restrict__ dst,
                          const int* __restrict__ rowptr, int* __restrict__ cursor,
                          int2* __restrict__ epk) {
    int e = blockIdx.x * blockDim.x + threadIdx.x;
    if (e >= N_EDGES) return;
    int d = dst[e];
    int pos = atomicAdd(&cursor[d], 1);
    epk[rowptr[d] + pos] = make_int2(e, src[e]);
}

// ======================= partial-sum reducer =======================
__global__ __launch_bounds__(256) void k_sumpart(const float* __restrict__ P, int n, float* __restrict__ S) {
    float s1 = 0.f, s2 = 0.f;
    int stride = gridDim.x * blockDim.x;
    for (int i = blockIdx.x * blockDim.x + threadIdx.x; i < n; i += stride) {
        s1 += P[2 * i]; s2 += P[2 * i + 1];
    }
    #pragma unroll
    for (int off = 32; off; off >>= 1) { s1 += __shfl_xor(s1, off); s2 += __shfl_xor(s2, off); }
    __shared__ float w1[4], w2[4];
    int w = threadIdx.x >> 6;
    if ((threadIdx.x & 63) == 0) { w1[w] = s1; w2[w] = s2; }
    __syncthreads();
    if (threadIdx.x == 0) {
        atomicAdd(S,     w1[0] + w1[1] + w1[2] + w1[3]);
        atomicAdd(S + 1, w2[0] + w2[1] + w2[2] + w2[3]);
    }
}

// ======================= conv1 node transform =======================
#define NT1 8
__global__ __launch_bounds__(256) void k_node1(
    const int* __restrict__ x, const float* __restrict__ emb,
    const float* __restrict__ Wl, const float* __restrict__ bl,
    const float* __restrict__ Wr, const float* __restrict__ br,
    u16* __restrict__ xl, u16* __restrict__ xr)
{
    __shared__ u16 wls[EMB * F1];
    __shared__ u16 wrs[EMB * F1];
    __shared__ float h0s[NT1 * EMB];
    __shared__ int xs[NT1];
    int tid = threadIdx.x;
    for (int i = tid; i < EMB * F1; i += 256) { wls[i] = f2b(Wl[i]); wrs[i] = f2b(Wr[i]); }
    float blr = bl[tid], brr = br[tid];
    __syncthreads();
    const int ntiles = N_NODES / NT1;   // 6250
    for (int tile = blockIdx.x; tile < ntiles; tile += gridDim.x) {
        int nb = tile * NT1;
        if (tid < NT1) xs[tid] = x[nb + tid];
        __syncthreads();
        for (int i = tid; i < NT1 * EMB; i += 256) {
            int nn = i / EMB, k = i - nn * EMB;
            h0s[i] = emb[(size_t)xs[nn] * EMB + k];
        }
        __syncthreads();
        float accl[NT1], accr[NT1];
        #pragma unroll
        for (int n = 0; n < NT1; n++) { accl[n] = blr; accr[n] = brr; }
        for (int k = 0; k < EMB; k++) {
            float wl_ = b2f(wls[k * F1 + tid]);
            float wr_ = b2f(wrs[k * F1 + tid]);
            #pragma unroll
            for (int n = 0; n < NT1; n++) {
                float h = h0s[n * EMB + k];
                accl[n] += h * wl_;
                accr[n] += h * wr_;
            }
        }
        #pragma unroll
        for (int n = 0; n < NT1; n++) {
            xl[(size_t)(nb + n) * F1 + tid] = f2b(accl[n]);
            xr[(size_t)(nb + n) * F1 + tid] = f2b(accr[n]);
        }
        __syncthreads();
    }
}

// ======================= conv1 fused edge-logit + online softmax + aggregate ===========
// block = node; 4 waves = 4 heads; ea rows via float4 VGPR-addressed loads (VMEM path;
// readfirstlane/SMEM would share lgkmcnt with the shuffle chain and serialize — round 7)
__global__ __launch_bounds__(256) void k_fused1(
    const int* __restrict__ rowptr, const int2* __restrict__ epk,
    const float* __restrict__ ea, const u16* __restrict__ xl, const u16* __restrict__ xr,
    const float* __restrict__ We, const float* __restrict__ att, const float* __restrict__ bias,
    float* __restrict__ out, float* __restrict__ Spart)
{
    int node = blockIdx.x;
    int tid = threadIdx.x;          // global column 0..255
    int h = tid >> 6, lane = tid & 63;
    float weR[EDIM];
    #pragma unroll
    for (int k = 0; k < EDIM; k++) weR[k] = We[k * F1 + tid];
    float attR = att[tid];
    float xr_d = b2f(xr[(size_t)node * F1 + tid]);
    int beg = rowptr[node], end = rowptr[node + 1];
    float m = -1e30f, acc = 0.f, dtot = 0.f;
    for (int j = beg; j < end; j++) {
        int2 p = epk[j];            // (edge, src)
        const float4* er4 = (const float4*)(ea + (size_t)p.x * EDIM);  // 112B row, 16B aligned
        float xl_s = b2f(xl[(size_t)p.y * F1 + tid]);
        float a0 = 0, a1 = 0;
        #pragma unroll
        for (int q = 0; q < 7; q++) {
            float4 v4 = er4[q];
            a0 += v4.x * weR[4 * q]     + v4.z * weR[4 * q + 2];
            a1 += v4.y * weR[4 * q + 1] + v4.w * weR[4 * q + 3];
        }
        float v = lrelu(xl_s + xr_d + a0 + a1) * attR;
        #pragma unroll
        for (int off = 32; off; off >>= 1) v += __shfl_xor(v, off);   // logit, in all lanes
        float mn = fmaxf(m, v);
        float scale = __expf(m - mn);       // 0 on first iteration (m=-1e30)
        float p_ = __expf(v - mn);
        acc  = acc  * scale + p_ * xl_s;
        dtot = dtot * scale + p_;
        m = mn;
    }
    float o = ((end > beg) ? acc / (dtot + EPS_SM) : 0.f) + bias[tid];
    out[(size_t)node * F1 + tid] = o;
    float s1 = o, s2 = o * o;
    #pragma unroll
    for (int off = 32; off; off >>= 1) { s1 += __shfl_xor(s1, off); s2 += __shfl_xor(s2, off); }
    __shared__ float ls1[4], ls2[4];
    if (lane == 0) { ls1[h] = s1; ls2[h] = s2; }
    __syncthreads();
    if (tid == 0) {
        Spart[(size_t)node * 2]     = ls1[0] + ls1[1] + ls1[2] + ls1[3];
        Spart[(size_t)node * 2 + 1] = ls2[0] + ls2[1] + ls2[2] + ls2[3];
    }
}

// ======================= LayerNorm apply (+ReLU) =======================
__global__ void k_ln_apply_relu(
    float* v, const float* __restrict__ w, const float* __restrict__ b,
    const float* __restrict__ S, int M, int C)
{
    int i = blockIdx.x * blockDim.x + threadIdx.x;
    if (i >= M) return;
    float mu = S[0] / (float)M;
    float var = S[1] / (float)M - mu * mu;
    float inv = 1.f / (sqrtf(fmaxf(var, 0.f)) + EPS_LN);
    int c = i % C;
    float y = (v[i] - mu) * inv * w[c] + b[c];
    v[i] = fmaxf(y, 0.f);
}

__global__ void k_ln_out(
    const float* __restrict__ v, const float* __restrict__ w, const float* __restrict__ b,
    const float* __restrict__ S, int M, int C, float* __restrict__ out)
{
    int i = blockIdx.x * blockDim.x + threadIdx.x;
    if (i >= M) return;
    float mu = S[0] / (float)M;
    float var = S[1] / (float)M - mu * mu;
    float inv = 1.f / (sqrtf(fmaxf(var, 0.f)) + EPS_LN);
    int c = i % C;
    out[i] = (v[i] - mu) * inv * w[c] + b[c];
}

// ======================= conv2 node transform =======================
#define NT2 16
__global__ __launch_bounds__(256) void k_node2(
    const float* __restrict__ h, const float* __restrict__ Wl, const float* __restrict__ bl,
    const float* __restrict__ Wr, const float* __restrict__ br,
    float* __restrict__ xl, float* __restrict__ xr)
{
    __shared__ u16 wls[F1 * OUTD];
    __shared__ u16 wrs[F1 * OUTD];
    __shared__ float hs[NT2 * F1];
    int tid = threadIdx.x;
    int w = tid >> 6, lane = tid & 63;
    for (int i = tid; i < F1 * OUTD; i += 256) { wls[i] = f2b(Wl[i]); wrs[i] = f2b(Wr[i]); }
    float blr = (lane < OUTD) ? bl[lane] : 0.f;
    float brr = (lane < OUTD) ? br[lane] : 0.f;
    __syncthreads();
    const int ntiles = N_NODES / NT2;   // 3125
    for (int tile = blockIdx.x; tile < ntiles; tile += gridDim.x) {
        int nb = tile * NT2;
        for (int i = tid; i < NT2 * F1; i += 256) hs[i] = h[(size_t)nb * F1 + i];
        __syncthreads();
        if (lane < OUTD) {
            float accl[4] = {blr, blr, blr, blr};
            float accr[4] = {brr, brr, brr, brr};
            int nl = w * 4;
            for (int k = 0; k < F1; k++) {
                float wl_ = b2f(wls[k * OUTD + lane]);
                float wr_ = b2f(wrs[k * OUTD + lane]);
                #pragma unroll
                for (int n = 0; n < 4; n++) {
                    float hv = hs[(nl + n) * F1 + k];
                    accl[n] += hv * wl_;
                    accr[n] += hv * wr_;
                }
            }
            #pragma unroll
            for (int n = 0; n < 4; n++) {
                xl[(size_t)(nb + nl + n) * OUTD + lane] = accl[n];
                xr[(size_t)(nb + nl + n) * OUTD + lane] = accr[n];
            }
        }
        __syncthreads();
    }
}

// ======================= conv2 fused (heads=1, C=50); wave = node =======================
__global__ __launch_bounds__(256) void k_fused2(
    const int* __restrict__ rowptr, const int2* __restrict__ epk,
    const float* __restrict__ ea, const float* __restrict__ xl, const float* __restrict__ xr,
    const float* __restrict__ We, const float* __restrict__ att, const float* __restrict__ bias,
    float* __restrict__ out, float* __restrict__ Spart)
{
    int w = threadIdx.x >> 6, lane = threadIdx.x & 63;
    int node = blockIdx.x * 4 + w;
    bool col = lane < OUTD;
    float weR[EDIM];
    #pragma unroll
    for (int k = 0; k < EDIM; k++) weR[k] = col ? We[k * OUTD + lane] : 0.f;
    float attR = col ? att[lane] : 0.f;
    float xr_d = col ? xr[(size_t)node * OUTD + lane] : 0.f;
    int beg = rowptr[node], end = rowptr[node + 1];
    float m = -1e30f, acc = 0.f, dtot = 0.f;
    for (int j = beg; j < end; j++) {
        int2 p = epk[j];
        const float4* er4 = (const float4*)(ea + (size_t)p.x * EDIM);
        float xl_s = col ? xl[(size_t)p.y * OUTD + lane] : 0.f;
        float a0 = 0, a1 = 0;
        #pragma unroll
        for (int q = 0; q < 7; q++) {
            float4 v4 = er4[q];
            a0 += v4.x * weR[4 * q]     + v4.z * weR[4 * q + 2];
            a1 += v4.y * weR[4 * q + 1] + v4.w * weR[4 * q + 3];
        }
        float v = col ? lrelu(xl_s + xr_d + a0 + a1) * attR : 0.f;
        #pragma unroll
        for (int off = 32; off; off >>= 1) v += __shfl_xor(v, off);
        float mn = fmaxf(m, v);
        float scale = __expf(m - mn);
        float p_ = __expf(v - mn);
        acc  = acc  * scale + p_ * xl_s;
        dtot = dtot * scale + p_;
        m = mn;
    }
    float s1 = 0.f, s2 = 0.f;
    if (col) {
        float o = ((end > beg) ? acc / (dtot + EPS_SM) : 0.f) + bias[lane];
        out[(size_t)node * OUTD + lane] = o;
        s1 = o; s2 = o * o;
    }
    #pragma unroll
    for (int off = 32; off; off >>= 1) { s1 += __shfl_xor(s1, off); s2 += __shfl_xor(s2, off); }
    __shared__ float ls1[4], ls2[4];
    if (lane == 0) { ls1[w] = s1; ls2[w] = s2; }
    __syncthreads();
    if (threadIdx.x == 0) {
        Spart[(size_t)blockIdx.x * 2]     = ls1[0] + ls1[1] + ls1[2] + ls1[3];
        Spart[(size_t)blockIdx.x * 2 + 1] = ls2[0] + ls2[1] + ls2[2] + ls2[3];
    }
}

extern "C" void kernel_launch(void* const* d_in, const int* in_sizes, int n_in,
                              void* d_out, int out_size, void* d_ws, size_t ws_size,
                              hipStream_t stream)
{
    const int*   x    = (const int*)d_in[0];
    const int*   ei   = (const int*)d_in[1];
    const int*   srcA = ei;
    const int*   dstA = ei + N_EDGES;
    const float* ea   = (const float*)d_in[2];
    const float* emb  = (const float*)d_in[3];
    const float* Wl1  = (const float*)d_in[4];
    const float* bl1  = (const float*)d_in[5];
    const float* Wr1  = (const float*)d_in[6];
    const float* br1  = (const float*)d_in[7];
    const float* We1  = (const float*)d_in[8];
    const float* att1 = (const float*)d_in[9];
    const float* bias1= (const float*)d_in[10];
    const float* ln1w = (const float*)d_in[11];
    const float* ln1b = (const float*)d_in[12];
    const float* Wl2  = (const float*)d_in[13];
    const float* bl2  = (const float*)d_in[14];
    const float* Wr2  = (const float*)d_in[15];
    const float* br2  = (const float*)d_in[16];
    const float* We2  = (const float*)d_in[17];
    const float* att2 = (const float*)d_in[18];
    const float* bias2= (const float*)d_in[19];
    const float* ln2w = (const float*)d_in[20];
    const float* ln2b = (const float*)d_in[21];

    // workspace layout (float offsets); peak ~26.87M floats = 107.5 MB (round-6 proven)
    float* W = (float*)d_ws;
    u16*   xl1b    = (u16*)W;                      // [0, 6.4M)
    u16*   xr1b    = (u16*)(W + 6400000);          // [6.4M, 12.8M)
    float* out1    = W + 12800000;                 // [12.8M, 25.6M)  (h1 in place)
    int2*  epk     = (int2*)(W + 25600000);        // [25.6M, 26.6M)
    int*   rowptr  = (int*)(W + 26600000);         // N+1
    int*   cnt     = (int*)(W + 26660000);         // N
    int*   cursor  = (int*)(W + 26710000);         // N
    float* Spart   = W + 26760000;                 // 2*N
    float* S       = W + 26870000;                 // 4
    // reuse (liveness-checked):
    float* xl2     = W;                            // [0, 2.5M)    xl1b dead after fused1
    float* xr2     = W + 2500000;                  // [2.5M, 5M)
    float* out2    = W + 6400000;                  // [6.4M, 8.9M) xr1b dead after fused1
    float* h1      = out1;

    hipMemsetAsync(cnt, 0, N_NODES * sizeof(int), stream);
    hipMemsetAsync(cursor, 0, N_NODES * sizeof(int), stream);
    hipMemsetAsync(S, 0, 4 * sizeof(float), stream);

    // CSR build
    k_hist<<<(N_EDGES + 255) / 256, 256, 0, stream>>>(dstA, cnt);
    k_scan<<<1, 1024, 0, stream>>>(cnt, rowptr);
    k_scatter<<<(N_EDGES + 255) / 256, 256, 0, stream>>>(srcA, dstA, rowptr, cursor, epk);

    // conv1
    k_node1<<<1024, 256, 0, stream>>>(x, emb, Wl1, bl1, Wr1, br1, xl1b, xr1b);
    k_fused1<<<N_NODES, 256, 0, stream>>>(rowptr, epk, ea, xl1b, xr1b, We1, att1, bias1, out1, Spart);
    k_sumpart<<<32, 256, 0, stream>>>(Spart, N_NODES, S);
    k_ln_apply_relu<<<(N_NODES * F1 + 255) / 256, 256, 0, stream>>>(out1, ln1w, ln1b, S, N_NODES * F1, F1);

    // conv2
    k_node2<<<1024, 256, 0, stream>>>(h1, Wl2, bl2, Wr2, br2, xl2, xr2);
    k_fused2<<<N_NODES / 4, 256, 0, stream>>>(rowptr, epk, ea, xl2, xr2, We2, att2, bias2, out2, Spart);
    k_sumpart<<<32, 256, 0, stream>>>(Spart, N_NODES / 4, S + 2);
    k_ln_out<<<(N_NODES * OUTD + 255) / 256, 256, 0, stream>>>(out2, ln2w, ln2b, S + 2, N_NODES * OUTD, OUTD, (float*)d_out);
}

// Round 10
// 1003.964 us; speedup vs baseline: 1.0018x; 1.0018x over previous
//
#include <hip/hip_runtime.h>

#define N_NODES 50000
#define N_EDGES 500000
#define EMB 50
#define HID 64
#define OUTD 50
#define EDIM 28
#define HEADS 4
#define F1 256              // HEADS*HID
#define NEG 0.2f
#define EPS_SM 1e-16f
#define EPS_LN 1e-5f

typedef unsigned short u16;
typedef unsigned int u32;

__device__ __forceinline__ float b2f(u16 u) { return __uint_as_float(((u32)u) << 16); }
__device__ __forceinline__ u16 f2b(float f) {
    u32 u = __float_as_uint(f);
    u32 r = (u + 0x7FFFu + ((u >> 16) & 1u)) >> 16;
    return (u16)r;
}
__device__ __forceinline__ float lrelu(float x) { return x > 0.f ? x : NEG * x; }

// ======================= CSR build =======================
__global__ void k_hist(const int* __restrict__ dst, int* __restrict__ cnt) {
    int e = blockIdx.x * blockDim.x + threadIdx.x;
    if (e < N_EDGES) atomicAdd(&cnt[dst[e]], 1);
}

__global__ __launch_bounds__(1024) void k_scan(const int* __restrict__ cnt, int* __restrict__ rowptr) {
    __shared__ int part[1024];
    int tid = threadIdx.x;
    const int CH = (N_NODES + 1023) / 1024;   // 49
    int beg = tid * CH;
    int end = beg + CH; if (end > N_NODES) end = N_NODES;
    int s = 0;
    for (int i = beg; i < end && i >= beg; i++) s += cnt[i];
    part[tid] = s;
    __syncthreads();
    for (int off = 1; off < 1024; off <<= 1) {
        int v = (tid >= off) ? part[tid - off] : 0;
        __syncthreads();
        part[tid] += v;
        __syncthreads();
    }
    int run = (tid == 0) ? 0 : part[tid - 1];
    for (int i = beg; i < end && i >= beg; i++) { rowptr[i] = run; run += cnt[i]; }
    if (tid == 1023) rowptr[N_NODES] = run;
}

__global__ void k_scatter(const int* __restrict__ src, const int* __restrict__ dst,
                          const int* __restrict__ rowptr, int* __restrict__ cursor,
                          int2* __restrict__ epk) {
    int e = blockIdx.x * blockDim.x + threadIdx.x;
    if (e >= N_EDGES) return;
    int d = dst[e];
    int pos = atomicAdd(&cursor[d], 1);
    epk[rowptr[d] + pos] = make_int2(e, src[e]);
}

// ======================= weight transpose: WeT1[c][k], We2T[c][k] (c padded to 64) =====
__global__ void k_wt(const float* __restrict__ We1, const float* __restrict__ We2,
                     float* __restrict__ WeT1, float* __restrict__ We2T) {
    int i = blockIdx.x * blockDim.x + threadIdx.x;
    if (i < F1 * EDIM) {
        int c = i / EDIM, k = i - c * EDIM;
        WeT1[i] = We1[k * F1 + c];
    } else if (i < F1 * EDIM + 64 * EDIM) {
        int j = i - F1 * EDIM;
        int c = j / EDIM, k = j - c * EDIM;
        We2T[j] = (c < OUTD) ? We2[k * OUTD + c] : 0.f;
    }
}

// ======================= partial-sum reducer =======================
__global__ __launch_bounds__(256) void k_sumpart(const float* __restrict__ P, int n, float* __restrict__ S) {
    float s1 = 0.f, s2 = 0.f;
    int stride = gridDim.x * blockDim.x;
    for (int i = blockIdx.x * blockDim.x + threadIdx.x; i < n; i += stride) {
        s1 += P[2 * i]; s2 += P[2 * i + 1];
    }
    #pragma unroll
    for (int off = 32; off; off >>= 1) { s1 += __shfl_xor(s1, off); s2 += __shfl_xor(s2, off); }
    __shared__ float w1[4], w2[4];
    int w = threadIdx.x >> 6;
    if ((threadIdx.x & 63) == 0) { w1[w] = s1; w2[w] = s2; }
    __syncthreads();
    if (threadIdx.x == 0) {
        atomicAdd(S,     w1[0] + w1[1] + w1[2] + w1[3]);
        atomicAdd(S + 1, w2[0] + w2[1] + w2[2] + w2[3]);
    }
}

// ======================= conv1 node transform =======================
#define NT1 8
__global__ __launch_bounds__(256) void k_node1(
    const int* __restrict__ x, const float* __restrict__ emb,
    const float* __restrict__ Wl, const float* __restrict__ bl,
    const float* __restrict__ Wr, const float* __restrict__ br,
    u16* __restrict__ xl, u16* __restrict__ xr)
{
    __shared__ u16 wls[EMB * F1];
    __shared__ u16 wrs[EMB * F1];
    __shared__ float h0s[NT1 * EMB];
    __shared__ int xs[NT1];
    int tid = threadIdx.x;
    for (int i = tid; i < EMB * F1; i += 256) { wls[i] = f2b(Wl[i]); wrs[i] = f2b(Wr[i]); }
    float blr = bl[tid], brr = br[tid];
    __syncthreads();
    const int ntiles = N_NODES / NT1;   // 6250
    for (int tile = blockIdx.x; tile < ntiles; tile += gridDim.x) {
        int nb = tile * NT1;
        if (tid < NT1) xs[tid] = x[nb + tid];
        __syncthreads();
        for (int i = tid; i < NT1 * EMB; i += 256) {
            int nn = i / EMB, k = i - nn * EMB;
            h0s[i] = emb[(size_t)xs[nn] * EMB + k];
        }
        __syncthreads();
        float accl[NT1], accr[NT1];
        #pragma unroll
        for (int n = 0; n < NT1; n++) { accl[n] = blr; accr[n] = brr; }
        for (int k = 0; k < EMB; k++) {
            float wl_ = b2f(wls[k * F1 + tid]);
            float wr_ = b2f(wrs[k * F1 + tid]);
            #pragma unroll
            for (int n = 0; n < NT1; n++) {
                float h = h0s[n * EMB + k];
                accl[n] += h * wl_;
                accr[n] += h * wr_;
            }
        }
        #pragma unroll
        for (int n = 0; n < NT1; n++) {
            xl[(size_t)(nb + n) * F1 + tid] = f2b(accl[n]);
            xr[(size_t)(nb + n) * F1 + tid] = f2b(accr[n]);
        }
        __syncthreads();
    }
}

// ======================= conv1 fused edge-logit + online softmax + aggregate ===========
// block = node; 4 waves = 4 heads. Weight column in 7 float4 registers (WeT transposed);
// __launch_bounds__(256,4) raises the VGPR cap so they aren't rematerialized per edge.
__global__ __launch_bounds__(256, 4) void k_fused1(
    const int* __restrict__ rowptr, const int2* __restrict__ epk,
    const float* __restrict__ ea, const u16* __restrict__ xl, const u16* __restrict__ xr,
    const float* __restrict__ WeT, const float* __restrict__ att, const float* __restrict__ bias,
    float* __restrict__ out, float* __restrict__ Spart)
{
    int node = blockIdx.x;
    int tid = threadIdx.x;          // global column 0..255
    int h = tid >> 6, lane = tid & 63;
    const float4* wt = (const float4*)(WeT + tid * EDIM);   // 28 floats = 112B, 16B-aligned
    float4 w0 = wt[0], w1 = wt[1], w2 = wt[2], w3 = wt[3], w4 = wt[4], w5 = wt[5], w6 = wt[6];
    float attR = att[tid];
    float xr_d = b2f(xr[((u32)node << 8) + tid]);
    int beg = rowptr[node], end = rowptr[node + 1];
    const float4* ea4 = (const float4*)ea;
    float m = -1e30f, acc = 0.f, dtot = 0.f;
    for (int j = beg; j < end; j++) {
        int2 p = epk[j];            // (edge, src)
        const float4* er4 = ea4 + p.x * 7;
        float xl_s = b2f(xl[((u32)p.y << 8) + tid]);
        float4 e0 = er4[0], e1 = er4[1], e2 = er4[2], e3 = er4[3], e4 = er4[4], e5 = er4[5], e6 = er4[6];
        float a0, a1;
        a0  = e0.x * w0.x + e0.z * w0.z;  a1  = e0.y * w0.y + e0.w * w0.w;
        a0 += e1.x * w1.x + e1.z * w1.z;  a1 += e1.y * w1.y + e1.w * w1.w;
        a0 += e2.x * w2.x + e2.z * w2.z;  a1 += e2.y * w2.y + e2.w * w2.w;
        a0 += e3.x * w3.x + e3.z * w3.z;  a1 += e3.y * w3.y + e3.w * w3.w;
        a0 += e4.x * w4.x + e4.z * w4.z;  a1 += e4.y * w4.y + e4.w * w4.w;
        a0 += e5.x * w5.x + e5.z * w5.z;  a1 += e5.y * w5.y + e5.w * w5.w;
        a0 += e6.x * w6.x + e6.z * w6.z;  a1 += e6.y * w6.y + e6.w * w6.w;
        float v = lrelu(xl_s + xr_d + a0 + a1) * attR;
        #pragma unroll
        for (int off = 32; off; off >>= 1) v += __shfl_xor(v, off);   // logit, in all lanes
        float mn = fmaxf(m, v);
        float scale = __expf(m - mn);       // 0 on first iteration (m=-1e30)
        float p_ = __expf(v - mn);
        acc  = acc  * scale + p_ * xl_s;
        dtot = dtot * scale + p_;
        m = mn;
    }
    float o = ((end > beg) ? acc / (dtot + EPS_SM) : 0.f) + bias[tid];
    out[((size_t)node << 8) + tid] = o;
    float s1 = o, s2 = o * o;
    #pragma unroll
    for (int off = 32; off; off >>= 1) { s1 += __shfl_xor(s1, off); s2 += __shfl_xor(s2, off); }
    __shared__ float ls1[4], ls2[4];
    if (lane == 0) { ls1[h] = s1; ls2[h] = s2; }
    __syncthreads();
    if (tid == 0) {
        Spart[(size_t)node * 2]     = ls1[0] + ls1[1] + ls1[2] + ls1[3];
        Spart[(size_t)node * 2 + 1] = ls2[0] + ls2[1] + ls2[2] + ls2[3];
    }
}

// ======================= LayerNorm apply (+ReLU) =======================
__global__ void k_ln_apply_relu(
    float* v, const float* __restrict__ w, const float* __restrict__ b,
    const float* __restrict__ S, int M, int C)
{
    int i = blockIdx.x * blockDim.x + threadIdx.x;
    if (i >= M) return;
    float mu = S[0] / (float)M;
    float var = S[1] / (float)M - mu * mu;
    float inv = 1.f / (sqrtf(fmaxf(var, 0.f)) + EPS_LN);
    int c = i % C;
    float y = (v[i] - mu) * inv * w[c] + b[c];
    v[i] = fmaxf(y, 0.f);
}

__global__ void k_ln_out(
    const float* __restrict__ v, const float* __restrict__ w, const float* __restrict__ b,
    const float* __restrict__ S, int M, int C, float* __restrict__ out)
{
    int i = blockIdx.x * blockDim.x + threadIdx.x;
    if (i >= M) return;
    float mu = S[0] / (float)M;
    float var = S[1] / (float)M - mu * mu;
    float inv = 1.f / (sqrtf(fmaxf(var, 0.f)) + EPS_LN);
    int c = i % C;
    out[i] = (v[i] - mu) * inv * w[c] + b[c];
}

// ======================= conv2 node transform =======================
#define NT2 16
__global__ __launch_bounds__(256) void k_node2(
    const float* __restrict__ h, const float* __restrict__ Wl, const float* __restrict__ bl,
    const float* __restrict__ Wr, const float* __restrict__ br,
    float* __restrict__ xl, float* __restrict__ xr)
{
    __shared__ u16 wls[F1 * OUTD];
    __shared__ u16 wrs[F1 * OUTD];
    __shared__ float hs[NT2 * F1];
    int tid = threadIdx.x;
    int w = tid >> 6, lane = tid & 63;
    for (int i = tid; i < F1 * OUTD; i += 256) { wls[i] = f2b(Wl[i]); wrs[i] = f2b(Wr[i]); }
    float blr = (lane < OUTD) ? bl[lane] : 0.f;
    float brr = (lane < OUTD) ? br[lane] : 0.f;
    __syncthreads();
    const int ntiles = N_NODES / NT2;   // 3125
    for (int tile = blockIdx.x; tile < ntiles; tile += gridDim.x) {
        int nb = tile * NT2;
        for (int i = tid; i < NT2 * F1; i += 256) hs[i] = h[(size_t)nb * F1 + i];
        __syncthreads();
        if (lane < OUTD) {
            float accl[4] = {blr, blr, blr, blr};
            float accr[4] = {brr, brr, brr, brr};
            int nl = w * 4;
            for (int k = 0; k < F1; k++) {
                float wl_ = b2f(wls[k * OUTD + lane]);
                float wr_ = b2f(wrs[k * OUTD + lane]);
                #pragma unroll
                for (int n = 0; n < 4; n++) {
                    float hv = hs[(nl + n) * F1 + k];
                    accl[n] += hv * wl_;
                    accr[n] += hv * wr_;
                }
            }
            #pragma unroll
            for (int n = 0; n < 4; n++) {
                xl[(size_t)(nb + nl + n) * OUTD + lane] = accl[n];
                xr[(size_t)(nb + nl + n) * OUTD + lane] = accr[n];
            }
        }
        __syncthreads();
    }
}

// ======================= conv2 fused (heads=1, C=50); wave = node =======================
__global__ __launch_bounds__(256, 4) void k_fused2(
    const int* __restrict__ rowptr, const int2* __restrict__ epk,
    const float* __restrict__ ea, const float* __restrict__ xl, const float* __restrict__ xr,
    const float* __restrict__ We2T, const float* __restrict__ att, const float* __restrict__ bias,
    float* __restrict__ out, float* __restrict__ Spart)
{
    int w = threadIdx.x >> 6, lane = threadIdx.x & 63;
    int node = blockIdx.x * 4 + w;
    bool col = lane < OUTD;
    const float4* wt = (const float4*)(We2T + lane * EDIM);   // padded rows: lane<64 all valid
    float4 w0 = wt[0], w1 = wt[1], w2 = wt[2], w3 = wt[3], w4 = wt[4], w5 = wt[5], w6 = wt[6];
    float attR = col ? att[lane] : 0.f;
    float xr_d = col ? xr[(u32)node * OUTD + lane] : 0.f;
    int beg = rowptr[node], end = rowptr[node + 1];
    const float4* ea4 = (const float4*)ea;
    float m = -1e30f, acc = 0.f, dtot = 0.f;
    for (int j = beg; j < end; j++) {
        int2 p = epk[j];
        const float4* er4 = ea4 + p.x * 7;
        float xl_s = col ? xl[(u32)p.y * OUTD + lane] : 0.f;
        float4 e0 = er4[0], e1 = er4[1], e2 = er4[2], e3 = er4[3], e4 = er4[4], e5 = er4[5], e6 = er4[6];
        float a0, a1;
        a0  = e0.x * w0.x + e0.z * w0.z;  a1  = e0.y * w0.y + e0.w * w0.w;
        a0 += e1.x * w1.x + e1.z * w1.z;  a1 += e1.y * w1.y + e1.w * w1.w;
        a0 += e2.x * w2.x + e2.z * w2.z;  a1 += e2.y * w2.y + e2.w * w2.w;
        a0 += e3.x * w3.x + e3.z * w3.z;  a1 += e3.y * w3.y + e3.w * w3.w;
        a0 += e4.x * w4.x + e4.z * w4.z;  a1 += e4.y * w4.y + e4.w * w4.w;
        a0 += e5.x * w5.x + e5.z * w5.z;  a1 += e5.y * w5.y + e5.w * w5.w;
        a0 += e6.x * w6.x + e6.z * w6.z;  a1 += e6.y * w6.y + e6.w * w6.w;
        float v = col ? lrelu(xl_s + xr_d + a0 + a1) * attR : 0.f;
        #pragma unroll
        for (int off = 32; off; off >>= 1) v += __shfl_xor(v, off);
        float mn = fmaxf(m, v);
        float scale = __expf(m - mn);
        float p_ = __expf(v - mn);
        acc  = acc  * scale + p_ * xl_s;
        dtot = dtot * scale + p_;
        m = mn;
    }
    float s1 = 0.f, s2 = 0.f;
    if (col) {
        float o = ((end > beg) ? acc / (dtot + EPS_SM) : 0.f) + bias[lane];
        out[(u32)node * OUTD + lane] = o;
        s1 = o; s2 = o * o;
    }
    #pragma unroll
    for (int off = 32; off; off >>= 1) { s1 += __shfl_xor(s1, off); s2 += __shfl_xor(s2, off); }
    __shared__ float ls1[4], ls2[4];
    if (lane == 0) { ls1[w] = s1; ls2[w] = s2; }
    __syncthreads();
    if (threadIdx.x == 0) {
        Spart[(size_t)blockIdx.x * 2]     = ls1[0] + ls1[1] + ls1[2] + ls1[3];
        Spart[(size_t)blockIdx.x * 2 + 1] = ls2[0] + ls2[1] + ls2[2] + ls2[3];
    }
}

extern "C" void kernel_launch(void* const* d_in, const int* in_sizes, int n_in,
                              void* d_out, int out_size, void* d_ws, size_t ws_size,
                              hipStream_t stream)
{
    const int*   x    = (const int*)d_in[0];
    const int*   ei   = (const int*)d_in[1];
    const int*   srcA = ei;
    const int*   dstA = ei + N_EDGES;
    const float* ea   = (const float*)d_in[2];
    const float* emb  = (const float*)d_in[3];
    const float* Wl1  = (const float*)d_in[4];
    const float* bl1  = (const float*)d_in[5];
    const float* Wr1  = (const float*)d_in[6];
    const float* br1  = (const float*)d_in[7];
    const float* We1  = (const float*)d_in[8];
    const float* att1 = (const float*)d_in[9];
    const float* bias1= (const float*)d_in[10];
    const float* ln1w = (const float*)d_in[11];
    const float* ln1b = (const float*)d_in[12];
    const float* Wl2  = (const float*)d_in[13];
    const float* bl2  = (const float*)d_in[14];
    const float* Wr2  = (const float*)d_in[15];
    const float* br2  = (const float*)d_in[16];
    const float* We2  = (const float*)d_in[17];
    const float* att2 = (const float*)d_in[18];
    const float* bias2= (const float*)d_in[19];
    const float* ln2w = (const float*)d_in[20];
    const float* ln2b = (const float*)d_in[21];

    // workspace layout (float offsets); peak ~26.90M floats = 107.6 MB (round-6 proven + 9KB)
    float* W = (float*)d_ws;
    u16*   xl1b    = (u16*)W;                      // [0, 6.4M)
    u16*   xr1b    = (u16*)(W + 6400000);          // [6.4M, 12.8M)
    float* out1    = W + 12800000;                 // [12.8M, 25.6M)  (h1 in place)
    int2*  epk     = (int2*)(W + 25600000);        // [25.6M, 26.6M)
    int*   rowptr  = (int*)(W + 26600000);         // N+1
    int*   cnt     = (int*)(W + 26660000);         // N
    int*   cursor  = (int*)(W + 26710000);         // N
    float* Spart   = W + 26760000;                 // 2*N
    float* S       = W + 26870000;                 // 4
    float* WeT1    = W + 26880000;                 // 256*28 = 7168
    float* We2T    = W + 26890000;                 // 64*28 = 1792
    // reuse (liveness-checked):
    float* xl2     = W;                            // [0, 2.5M)    xl1b dead after fused1
    float* xr2     = W + 2500000;                  // [2.5M, 5M)
    float* out2    = W + 6400000;                  // [6.4M, 8.9M) xr1b dead after fused1
    float* h1      = out1;

    hipMemsetAsync(cnt, 0, N_NODES * sizeof(int), stream);
    hipMemsetAsync(cursor, 0, N_NODES * sizeof(int), stream);
    hipMemsetAsync(S, 0, 4 * sizeof(float), stream);

    // CSR build + weight transpose
    k_hist<<<(N_EDGES + 255) / 256, 256, 0, stream>>>(dstA, cnt);
    k_scan<<<1, 1024, 0, stream>>>(cnt, rowptr);
    k_scatter<<<(N_EDGES + 255) / 256, 256, 0, stream>>>(srcA, dstA, rowptr, cursor, epk);
    k_wt<<<(F1 * EDIM + 64 * EDIM + 255) / 256, 256, 0, stream>>>(We1, We2, WeT1, We2T);

    // conv1
    k_node1<<<1024, 256, 0, stream>>>(x, emb, Wl1, bl1, Wr1, br1, xl1b, xr1b);
    k_fused1<<<N_NODES, 256, 0, stream>>>(rowptr, epk, ea, xl1b, xr1b, WeT1, att1, bias1, out1, Spart);
    k_sumpart<<<32, 256, 0, stream>>>(Spart, N_NODES, S);
    k_ln_apply_relu<<<(N_NODES * F1 + 255) / 256, 256, 0, stream>>>(out1, ln1w, ln1b, S, N_NODES * F1, F1);

    // conv2
    k_node2<<<1024, 256, 0, stream>>>(h1, Wl2, bl2, Wr2, br2, xl2, xr2);
    k_fused2<<<N_NODES / 4, 256, 0, stream>>>(rowptr, epk, ea, xl2, xr2, We2T, att2, bias2, out2, Spart);
    k_sumpart<<<32, 256, 0, stream>>>(Spart, N_NODES / 4, S + 2);
    k_ln_out<<<(N_NODES * OUTD + 255) / 256, 256, 0, stream>>>(out2, ln2w, ln2b, S + 2, N_NODES * OUTD, OUTD, (float*)d_out);
}